// Round 1
// baseline (269.144 us; speedup 1.0000x reference)
//
#include <hip/hip_runtime.h>
#include <hip/hip_bf16.h>

// DARTS MixedOp. B=64, C=128, H=W=32. Per-sample top-k(2) masked-softmax gate
// over 8 ops. Inputs fp32, outputs fp32.
//
// R11: 5 -> 2 dispatches.
//  K1 (k_front_all): gate compute INLINED per block (no producer dependency);
//     pools+skip+out-init+first-dw as before; extra blocks do pw-weight bf16
//     prep and the gates/cnum/cops/outw buffer writes for K2.
//  K2 (k_tail): fused pw_mid + dw2 + pw_final. Per (b, hw-tile) block:
//     recompute mid-pw for the K+1 halo rows via MFMA (A staged with
//     zero-padded stage_bt_z), keep B in LDS only (relu'd bf16, stride 196us
//     -> conflict-free b64 lanes), depthwise via register sliding window
//     (thread's channel fixed -> dw weights in VGPRs), then final MFMA and
//     float4 RMW into out. B4/B5/P4/P5 global buffers eliminated.
//
// ws: gates @0 | cnum @2048 | cops @2304 | Wbf[6][128][128] bf16 @4096 |
// 4 bf16 bufs of 16.8MB @200704 (A4 A5 P6 P7) = ~67MB.

#define BN_SCALE 0.9999950000374997f  // 1/sqrt(1+1e-5)
#define BB 64
#define CC 128
#define HH 32
#define WW 32
#define PLANE (HH*WW)          // 1024
#define SAMP (CC*PLANE)        // 131072
#define NOUT0 (BB*SAMP)        // 8388608

typedef __attribute__((ext_vector_type(8))) short bf16x8;
typedef __attribute__((ext_vector_type(4))) float f32x4;

__device__ __forceinline__ float us2f(unsigned int u) {
    unsigned int x = (u & 0xffffu) << 16;
    float f; __builtin_memcpy(&f, &x, 4); return f;
}
__device__ __forceinline__ unsigned short f2us(float f) {
    __hip_bfloat16 h = __float2bfloat16(f);
    unsigned short u; __builtin_memcpy(&u, &h, 2); return u;
}

// ---------------------------------------------------------------- gates
// Identical math everywhere (deterministic) so inline copies agree with the
// buffer written by the role block.
__device__ __forceinline__ void compute_gates(const float* __restrict__ wlog,
                                              const void* __restrict__ topp,
                                              int b, float* g) {
    int top = -1;                           // robust `top` parse
    {
        unsigned int u0 = *(const unsigned int*)topp;
        int i32 = (int)u0;
        if (i32 >= 1 && i32 <= 8) top = i32;
        else {
            float f32v; __builtin_memcpy(&f32v, &u0, 4);
            if (f32v >= 1.f && f32v <= 8.f) top = (int)(f32v + 0.5f);
            else { float fb = us2f(u0); if (fb >= 1.f && fb <= 8.f) top = (int)(fb + 0.5f); }
        }
        if (top < 1 || top > 8) top = 2;
    }
    float lw[8];
    #pragma unroll
    for (int i = 0; i < 8; ++i) lw[i] = wlog[b * 8 + i];
    bool sel[8] = {false,false,false,false,false,false,false,false};
    for (int t = 0; t < top; ++t) {         // lax.top_k tie-break: lowest index
        int best = -1; float bv = -3.4e38f;
        #pragma unroll
        for (int i = 0; i < 8; ++i)
            if (!sel[i] && lw[i] > bv) { bv = lw[i]; best = i; }
        if (best >= 0) sel[best] = true;
    }
    float m = -3.4e38f;
    #pragma unroll
    for (int i = 0; i < 8; ++i) if (sel[i] && lw[i] > m) m = lw[i];
    float s = 0.f, e[8];
    #pragma unroll
    for (int i = 0; i < 8; ++i) { e[i] = sel[i] ? expf(lw[i] - m) : 0.f; s += e[i]; }
    float inv = (s > 0.f) ? 1.f / s : 0.f;
    #pragma unroll
    for (int i = 0; i < 8; ++i)
        g[i] = (s > 0.f) ? e[i] * inv : (sel[i] ? 1.f / (float)top : 0.f);
}

// ------------------------------------------- depthwise conv helper (K1)
template <int K, int DIL>
__device__ __forceinline__ void dw_comp(const float* __restrict__ sx,
                                        const float* __restrict__ wd, int c,
                                        unsigned short* __restrict__ opp) {
    constexpr int PAD = (K / 2) * DIL;
    float wk[K * K];
    #pragma unroll
    for (int i = 0; i < K * K; ++i) wk[i] = wd[c * K * K + i];
    #pragma unroll
    for (int j = 0; j < 4; ++j) {
        int px = threadIdx.x + j * 256;
        int h = px >> 5, w = px & 31;
        float acc = 0.f;
        #pragma unroll
        for (int ky = 0; ky < K; ++ky) {
            int ih = h + ky * DIL - PAD;
            if ((unsigned)ih >= HH) continue;
            #pragma unroll
            for (int kx = 0; kx < K; ++kx) {
                int iw = w + kx * DIL - PAD;
                if ((unsigned)iw >= WW) continue;
                acc = fmaf(wk[ky * K + kx], sx[ih * WW + iw], acc);
            }
        }
        opp[px] = f2us(acc);
    }
}

// ------- K1: pools + skip + out init + first dw of all 4 conv ops,
//             plus (aux blocks) weight prep and gate-buffer writes.
__global__ __launch_bounds__(256) void
k_front_all(const float* __restrict__ x,
            const float* __restrict__ w4, const float* __restrict__ w5,
            const float* __restrict__ w6, const float* __restrict__ w7,
            const float* __restrict__ wlog, const void* __restrict__ topp,
            const float* __restrict__ pw0, const float* __restrict__ pw1,
            const float* __restrict__ pw2, const float* __restrict__ pw3,
            const float* __restrict__ pw4, const float* __restrict__ pw5,
            float* __restrict__ gates,
            int* __restrict__ cnum, int* __restrict__ cops,
            float* __restrict__ out_w,
            unsigned short* __restrict__ Wbf,
            float* __restrict__ out,
            unsigned short* __restrict__ A4, unsigned short* __restrict__ A5,
            unsigned short* __restrict__ P6, unsigned short* __restrict__ P7) {
    if (blockIdx.x >= BB * CC) {
        int aux = blockIdx.x - BB * CC;
        if (aux < 384) {                         // pw weight fp32->bf16 prep
            int idx = aux * 256 + threadIdx.x;   // 6*16384 = 384*256
            int mat = idx >> 14, e = idx & 16383;
            const float* src; float s = 1.f;
            switch (mat) {                       // block-uniform
                case 0:  src = pw0; s = BN_SCALE; break;  // sc3_p1 (mid, BN folded)
                case 1:  src = pw1; s = BN_SCALE; break;  // sc5_p1
                case 2:  src = pw2; break;                // sc3_p2
                case 3:  src = pw3; break;                // sc5_p2
                case 4:  src = pw4; break;                // dc3_p
                default: src = pw5; break;                // dc5_p
            }
            Wbf[idx] = f2us(src[e] * s);
        } else if (threadIdx.x < BB) {           // gate-buffer role block
            int b = threadIdx.x;
            float g[8];
            compute_gates(wlog, topp, b, g);
            #pragma unroll
            for (int i = 0; i < 8; ++i) {
                out_w[b * 8 + i] = wlog[b * 8 + i];   // output 1: logit clone
                gates[b * 8 + i] = g[i];
            }
            int n = 0;
            #pragma unroll
            for (int i = 4; i < 8; ++i)
                if (g[i] > 0.f) { if (n < 4) cops[b * 4 + n] = i; ++n; }
            cnum[b] = (n < 4) ? n : 4;
        }
        return;
    }
    int plane = blockIdx.x;            // b*128 + c
    int b = plane >> 7, c = plane & 127;
    float g[8];
    compute_gates(wlog, topp, b, g);   // inline: no producer-kernel dependency
    float g1 = g[1] * BN_SCALE;
    float g2 = g[2] * BN_SCALE;
    float g3 = g[3];
    float g4 = g[4], g5 = g[5], g6 = g[6], g7 = g[7];
    bool haspool = (g1 != 0.f) | (g2 != 0.f) | (g3 != 0.f);
    bool hasdw   = (g4 != 0.f) | (g5 != 0.f) | (g6 != 0.f) | (g7 != 0.f);
    float* op = out + (size_t)plane * PLANE;
    if (!haspool && !hasdw) {
        ((float4*)op)[threadIdx.x] = make_float4(0.f, 0.f, 0.f, 0.f);
        return;
    }
    __shared__ float sxr[PLANE];       // raw x (pools/skip)
    __shared__ float sxf[PLANE];       // relu(x) (dw)
    {
        float4 v = ((const float4*)(x + (size_t)plane * PLANE))[threadIdx.x];
        ((float4*)sxr)[threadIdx.x] = v;
        ((float4*)sxf)[threadIdx.x] =
            make_float4(fmaxf(v.x, 0.f), fmaxf(v.y, 0.f),
                        fmaxf(v.z, 0.f), fmaxf(v.w, 0.f));
    }
    __syncthreads();

    // ---- out init: pools + skip (or zeros)
    if (haspool) {
        #pragma unroll
        for (int j = 0; j < 4; ++j) {
            int px = threadIdx.x + j * 256;
            int h = px >> 5, w = px & 31;
            float mx = -3.4e38f, sm = 0.f;
            int cnt = 0;
            #pragma unroll
            for (int dh = -1; dh <= 1; ++dh) {
                int ih = h + dh;
                if ((unsigned)ih >= HH) continue;
                #pragma unroll
                for (int dw = -1; dw <= 1; ++dw) {
                    int iw = w + dw;
                    if ((unsigned)iw >= WW) continue;
                    float v = sxr[ih * WW + iw];
                    mx = fmaxf(mx, v);
                    sm += v;
                    ++cnt;
                }
            }
            op[px] = g1 * mx + g2 * (sm / (float)cnt) + g3 * sxr[px];
        }
    } else {
        ((float4*)op)[threadIdx.x] = make_float4(0.f, 0.f, 0.f, 0.f);
    }

    // ---- first dw for gated conv ops
    size_t off = (size_t)plane * PLANE;
    if (g4 != 0.f) dw_comp<3, 1>(sxf, w4, c, A4 + off);
    if (g5 != 0.f) dw_comp<5, 1>(sxf, w5, c, A5 + off);
    if (g6 != 0.f) dw_comp<3, 2>(sxf, w6, c, P6 + off);
    if (g7 != 0.f) dw_comp<5, 2>(sxf, w7, c, P7 + off);
}

// ---------------- MFMA pw building blocks -------------------------------
// Orientation: m=hw, n=co. A = In^T tile (LDS, 64hw x 128ci, row stride 130
// ushorts = 65 dwords -> bank stride 1), B = W bf16 (direct global, L2-hot).

__device__ __forceinline__ void stage_bt(unsigned int* __restrict__ BtU,
                                         const unsigned short* __restrict__ A,
                                         int hw0, float s) {
    unsigned short* Bs = (unsigned short*)BtU;
    #pragma unroll
    for (int i = 0; i < 16; ++i) {
        int idx = threadIdx.x + i * 256;       // 4096 = 128ci x 32 hw-pairs
        int ci = idx >> 5, p = idx & 31;
        unsigned int raw = *(const unsigned int*)(A + (size_t)ci * PLANE + hw0 + 2 * p);
        Bs[(2 * p) * 130 + ci]     = f2us(us2f(raw) * s);
        Bs[(2 * p + 1) * 130 + ci] = f2us(us2f(raw >> 16) * s);
    }
}

// zero-padded variant for halo rows (hw0 may run off the plane)
__device__ __forceinline__ void stage_bt_z(unsigned int* __restrict__ BtU,
                                           const unsigned short* __restrict__ A,
                                           int hw0) {
    unsigned short* Bs = (unsigned short*)BtU;
    #pragma unroll
    for (int i = 0; i < 16; ++i) {
        int idx = threadIdx.x + i * 256;
        int ci = idx >> 5, p = idx & 31;
        int pg = hw0 + 2 * p;
        unsigned int raw = 0u;
        if ((unsigned)pg < (unsigned)PLANE)
            raw = *(const unsigned int*)(A + (size_t)ci * PLANE + pg);
        Bs[(2 * p) * 130 + ci]     = (unsigned short)(raw & 0xffffu);
        Bs[(2 * p + 1) * 130 + ci] = (unsigned short)(raw >> 16);
    }
}

__device__ __forceinline__ bf16x8 afrag(const unsigned int* __restrict__ BtU,
                                        int r, int ko2) {
    union { unsigned int u[4]; bf16x8 v; } f;
    #pragma unroll
    for (int j = 0; j < 4; ++j) f.u[j] = BtU[r * 65 + ko2 + j];
    return f.v;
}

// ---- fused sep-conv tail: mid-pw over K+1 halo rows (MFMA, B kept in LDS,
//      relu'd bf16), then depthwise KxK via register sliding window, output
//      (scaled by gs) into the BtU staging buffer for the final MFMA.
template <int K>
__device__ __forceinline__ void
sep_to_bt(unsigned int* __restrict__ BtU, unsigned short* __restrict__ Braw,
          const unsigned short* __restrict__ Asrc,
          const unsigned short* __restrict__ Wmid,
          const float* __restrict__ wd, int hwt, float gs) {
    constexpr int PAD = K / 2, NR = K + 1, NSEG = NR / 2, S = 196;
    int wave = threadIdx.x >> 6, lane = threadIdx.x & 63;
    int q = lane >> 4, mm = lane & 15;
    int r = wave * 16 + mm;
    int rbase = 2 * hwt - PAD;                 // first staged image row
    for (int seg = 0; seg < NSEG; ++seg) {
        if (seg) __syncthreads();              // prev seg's afrag reads done
        stage_bt_z(BtU, Asrc, rbase * 32 + seg * 64);
        __syncthreads();
        f32x4 accB[8];
        #pragma unroll
        for (int i = 0; i < 8; ++i) accB[i] = (f32x4){0.f, 0.f, 0.f, 0.f};
        #pragma unroll
        for (int kb = 0; kb < 4; ++kb) {
            bf16x8 a = afrag(BtU, r, kb * 16 + q * 4);
            #pragma unroll
            for (int nt = 0; nt < 8; ++nt) {
                bf16x8 bv = *(const bf16x8*)(Wmid + (nt * 16 + mm) * CC + kb * 32 + q * 8);
                accB[nt] = __builtin_amdgcn_mfma_f32_16x16x32_bf16(a, bv, accB[nt], 0, 0, 0);
            }
        }
        int pxb = seg * 64 + wave * 16 + q * 4;   // local px within NR rows
        #pragma unroll
        for (int nt = 0; nt < 8; ++nt) {
            int co = nt * 16 + mm;
            ushort4 v;
            v.x = f2us(fmaxf(accB[nt][0], 0.f));   // relu folded (bit-equal to
            v.y = f2us(fmaxf(accB[nt][1], 0.f));   // round-then-relu for bf16)
            v.z = f2us(fmaxf(accB[nt][2], 0.f));
            v.w = f2us(fmaxf(accB[nt][3], 0.f));
            *(ushort4*)(Braw + (size_t)co * S + pxb) = v;
        }
    }
    __syncthreads();                           // Braw complete; BtU free

    // depthwise KxK: thread's channel fixed -> weights in VGPRs; sliding
    // window over 32 cols. Braw row r6 = image row rbase+r6.
    int ci = threadIdx.x & 127, h = threadIdx.x >> 7;   // h: output row 2t+h
    float wk[K * K];
    #pragma unroll
    for (int i = 0; i < K * K; ++i) wk[i] = wd[ci * K * K + i];
    float acc[32];
    #pragma unroll
    for (int w = 0; w < 32; ++w) acc[w] = 0.f;
    const unsigned short* rowp = Braw + (size_t)ci * S + h * 32;
    #pragma unroll
    for (int ky = 0; ky < K; ++ky) {           // input row r6 = h + ky
        float win[40];                         // cols -4..35 (OOB chunks = 0)
        #pragma unroll
        for (int k = 0; k < 10; ++k) {
            if (k == 0 || k == 9) {
                win[4*k] = win[4*k+1] = win[4*k+2] = win[4*k+3] = 0.f;
            } else {
                ushort4 v = *(const ushort4*)(rowp + ky * 32 + (k - 1) * 4);
                win[4*k]   = us2f(v.x);
                win[4*k+1] = us2f(v.y);
                win[4*k+2] = us2f(v.z);
                win[4*k+3] = us2f(v.w);
            }
        }
        #pragma unroll
        for (int kx = 0; kx < K; ++kx) {
            float f = wk[ky * K + kx];
            #pragma unroll
            for (int w = 0; w < 32; ++w)
                acc[w] = fmaf(f, win[w + kx - PAD + 4], acc[w]);
        }
    }
    unsigned short* Bs = (unsigned short*)BtU;
    #pragma unroll
    for (int w = 0; w < 32; ++w)
        Bs[(h * 32 + w) * 130 + ci] = f2us(acc[w] * gs);
    __syncthreads();                           // BtU ready for final MFMA
}

// ------------- K2: fused mid-pw + dw2 + final-pw, float4 RMW into out
__global__ __launch_bounds__(256, 2) void
k_tail(const unsigned short* __restrict__ A4,
       const unsigned short* __restrict__ A5,
       const unsigned short* __restrict__ P6,
       const unsigned short* __restrict__ P7,
       const unsigned short* __restrict__ Wbf,
       const float* __restrict__ gates,
       const int* __restrict__ cnum, const int* __restrict__ cops,
       const float* __restrict__ wd3, const float* __restrict__ wd5,
       float* __restrict__ out) {
    int blk = blockIdx.x;              // b*16 + hwt
    int hwt = blk & 15;
    int b = blk >> 4;
    int n = cnum[b];
    if (n == 0) return;                // out already holds pools/skip/zeros
    int hw0 = hwt * 64;
    int wave = threadIdx.x >> 6, lane = threadIdx.x & 63;
    int q = lane >> 4, mm = lane & 15;
    int r = wave * 16 + mm;
    __shared__ unsigned int BtU[64 * 65];           // 16.6 KB
    __shared__ unsigned short Braw[128 * 196];      // 50.2 KB (stride 196us:
                                                    // dword-stride 98 -> b64
                                                    // lanes conflict-free)
    f32x4 acc[8];
    #pragma unroll
    for (int i = 0; i < 8; ++i) acc[i] = (f32x4){0.f, 0.f, 0.f, 0.f};
    for (int t = 0; t < n; ++t) {
        int op = cops[b * 4 + t];
        float gs = gates[b * 8 + op] * BN_SCALE;
        if (t) __syncthreads();        // prev op's BtU readers done
        if (op >= 6) {                 // dil convs: dw already done (P6/P7)
            stage_bt(BtU, (op == 6 ? P6 : P7) + (size_t)b * SAMP, hw0, gs);
            __syncthreads();
        } else if (op == 4) {
            sep_to_bt<3>(BtU, Braw, A4 + (size_t)b * SAMP, Wbf, wd3, hwt, gs);
        } else {
            sep_to_bt<5>(BtU, Braw, A5 + (size_t)b * SAMP, Wbf + 16384, wd5, hwt, gs);
        }
        const unsigned short* Wb = Wbf + (op - 2) * 16384;
        #pragma unroll
        for (int kb = 0; kb < 4; ++kb) {
            bf16x8 a = afrag(BtU, r, kb * 16 + q * 4);
            #pragma unroll
            for (int nt = 0; nt < 8; ++nt) {
                bf16x8 bv = *(const bf16x8*)(Wb + (nt * 16 + mm) * CC + kb * 32 + q * 8);
                acc[nt] = __builtin_amdgcn_mfma_f32_16x16x32_bf16(a, bv, acc[nt], 0, 0, 0);
            }
        }
    }
    int hwbase = hw0 + wave * 16 + q * 4;
    #pragma unroll
    for (int nt = 0; nt < 8; ++nt) {
        int co = nt * 16 + mm;
        float* p = out + (size_t)(b * CC + co) * PLANE + hwbase;
        float4 o = *(float4*)p;
        o.x += acc[nt][0]; o.y += acc[nt][1];
        o.z += acc[nt][2]; o.w += acc[nt][3];
        *(float4*)p = o;
    }
}

// ---------------------------------------------------------------- launch
extern "C" void kernel_launch(void* const* d_in, const int* in_sizes, int n_in,
                              void* d_out, int out_size, void* d_ws, size_t ws_size,
                              hipStream_t stream) {
    const float* x      = (const float*)d_in[0];
    const float* wlog   = (const float*)d_in[1];
    const float* sc3_d1 = (const float*)d_in[2];
    const float* sc3_p1 = (const float*)d_in[3];
    const float* sc3_d2 = (const float*)d_in[4];
    const float* sc3_p2 = (const float*)d_in[5];
    const float* sc5_d1 = (const float*)d_in[6];
    const float* sc5_p1 = (const float*)d_in[7];
    const float* sc5_d2 = (const float*)d_in[8];
    const float* sc5_p2 = (const float*)d_in[9];
    const float* dc3_d  = (const float*)d_in[10];
    const float* dc3_p  = (const float*)d_in[11];
    const float* dc5_d  = (const float*)d_in[12];
    const float* dc5_p  = (const float*)d_in[13];
    const void* topp    = d_in[14];

    float* out  = (float*)d_out;
    float* outw = out + NOUT0;

    float* gates = (float*)d_ws;
    int*   cnum  = (int*)((char*)d_ws + 2048);
    int*   cops  = (int*)((char*)d_ws + 2304);
    unsigned short* Wbf  = (unsigned short*)((char*)d_ws + 4096);   // 6*32KB
    unsigned short* base = (unsigned short*)((char*)d_ws + 200704);
    unsigned short* A4 = base;
    unsigned short* A5 = base + (size_t)NOUT0;
    unsigned short* P6 = base + (size_t)NOUT0 * 2;
    unsigned short* P7 = base + (size_t)NOUT0 * 3;

    k_front_all<<<BB * CC + 385, 256, 0, stream>>>(
        x, sc3_d1, sc5_d1, dc3_d, dc5_d,
        wlog, topp,
        sc3_p1, sc5_p1, sc3_p2, sc5_p2, dc3_p, dc5_p,
        gates, cnum, cops, outw, Wbf,
        out, A4, A5, P6, P7);
    k_tail<<<BB * 16, 256, 0, stream>>>(A4, A5, P6, P7, Wbf,
                                        gates, cnum, cops,
                                        sc3_d2, sc5_d2, out);
}

// Round 2
// 264.367 us; speedup vs baseline: 1.0181x; 1.0181x over previous
//
#include <hip/hip_runtime.h>
#include <hip/hip_bf16.h>

// DARTS MixedOp. B=64, C=128, H=W=32. Per-sample top-k(2) masked-softmax gate
// over 8 ops. Inputs fp32, outputs fp32.
//
// R12: same 2-dispatch structure as R11; fixes k_tail scratch spills.
//  R11's dw sliding window (acc[32]+win[40]+wk[25] live) blew the VGPR
//  budget -> 190MB of scratch writes, 142us. R12 chunks the dw into 4x8
//  columns (acc[8]+win[16]+wk[25]); same per-output FMA order ->
//  bit-identical math, no scratch.
//
// ws: gates @0 | cnum @2048 | cops @2304 | Wbf[6][128][128] bf16 @4096 |
// 4 bf16 bufs of 16.8MB @200704 (A4 A5 P6 P7) = ~67MB.

#define BN_SCALE 0.9999950000374997f  // 1/sqrt(1+1e-5)
#define BB 64
#define CC 128
#define HH 32
#define WW 32
#define PLANE (HH*WW)          // 1024
#define SAMP (CC*PLANE)        // 131072
#define NOUT0 (BB*SAMP)        // 8388608

typedef __attribute__((ext_vector_type(8))) short bf16x8;
typedef __attribute__((ext_vector_type(4))) float f32x4;

__device__ __forceinline__ float us2f(unsigned int u) {
    unsigned int x = (u & 0xffffu) << 16;
    float f; __builtin_memcpy(&f, &x, 4); return f;
}
__device__ __forceinline__ unsigned short f2us(float f) {
    __hip_bfloat16 h = __float2bfloat16(f);
    unsigned short u; __builtin_memcpy(&u, &h, 2); return u;
}

// ---------------------------------------------------------------- gates
// Identical math everywhere (deterministic) so inline copies agree with the
// buffer written by the role block.
__device__ __forceinline__ void compute_gates(const float* __restrict__ wlog,
                                              const void* __restrict__ topp,
                                              int b, float* g) {
    int top = -1;                           // robust `top` parse
    {
        unsigned int u0 = *(const unsigned int*)topp;
        int i32 = (int)u0;
        if (i32 >= 1 && i32 <= 8) top = i32;
        else {
            float f32v; __builtin_memcpy(&f32v, &u0, 4);
            if (f32v >= 1.f && f32v <= 8.f) top = (int)(f32v + 0.5f);
            else { float fb = us2f(u0); if (fb >= 1.f && fb <= 8.f) top = (int)(fb + 0.5f); }
        }
        if (top < 1 || top > 8) top = 2;
    }
    float lw[8];
    #pragma unroll
    for (int i = 0; i < 8; ++i) lw[i] = wlog[b * 8 + i];
    bool sel[8] = {false,false,false,false,false,false,false,false};
    for (int t = 0; t < top; ++t) {         // lax.top_k tie-break: lowest index
        int best = -1; float bv = -3.4e38f;
        #pragma unroll
        for (int i = 0; i < 8; ++i)
            if (!sel[i] && lw[i] > bv) { bv = lw[i]; best = i; }
        if (best >= 0) sel[best] = true;
    }
    float m = -3.4e38f;
    #pragma unroll
    for (int i = 0; i < 8; ++i) if (sel[i] && lw[i] > m) m = lw[i];
    float s = 0.f, e[8];
    #pragma unroll
    for (int i = 0; i < 8; ++i) { e[i] = sel[i] ? expf(lw[i] - m) : 0.f; s += e[i]; }
    float inv = (s > 0.f) ? 1.f / s : 0.f;
    #pragma unroll
    for (int i = 0; i < 8; ++i)
        g[i] = (s > 0.f) ? e[i] * inv : (sel[i] ? 1.f / (float)top : 0.f);
}

// ------------------------------------------- depthwise conv helper (K1)
template <int K, int DIL>
__device__ __forceinline__ void dw_comp(const float* __restrict__ sx,
                                        const float* __restrict__ wd, int c,
                                        unsigned short* __restrict__ opp) {
    constexpr int PAD = (K / 2) * DIL;
    float wk[K * K];
    #pragma unroll
    for (int i = 0; i < K * K; ++i) wk[i] = wd[c * K * K + i];
    #pragma unroll
    for (int j = 0; j < 4; ++j) {
        int px = threadIdx.x + j * 256;
        int h = px >> 5, w = px & 31;
        float acc = 0.f;
        #pragma unroll
        for (int ky = 0; ky < K; ++ky) {
            int ih = h + ky * DIL - PAD;
            if ((unsigned)ih >= HH) continue;
            #pragma unroll
            for (int kx = 0; kx < K; ++kx) {
                int iw = w + kx * DIL - PAD;
                if ((unsigned)iw >= WW) continue;
                acc = fmaf(wk[ky * K + kx], sx[ih * WW + iw], acc);
            }
        }
        opp[px] = f2us(acc);
    }
}

// ------- K1: pools + skip + out init + first dw of all 4 conv ops,
//             plus (aux blocks) weight prep and gate-buffer writes.
__global__ __launch_bounds__(256) void
k_front_all(const float* __restrict__ x,
            const float* __restrict__ w4, const float* __restrict__ w5,
            const float* __restrict__ w6, const float* __restrict__ w7,
            const float* __restrict__ wlog, const void* __restrict__ topp,
            const float* __restrict__ pw0, const float* __restrict__ pw1,
            const float* __restrict__ pw2, const float* __restrict__ pw3,
            const float* __restrict__ pw4, const float* __restrict__ pw5,
            float* __restrict__ gates,
            int* __restrict__ cnum, int* __restrict__ cops,
            float* __restrict__ out_w,
            unsigned short* __restrict__ Wbf,
            float* __restrict__ out,
            unsigned short* __restrict__ A4, unsigned short* __restrict__ A5,
            unsigned short* __restrict__ P6, unsigned short* __restrict__ P7) {
    if (blockIdx.x >= BB * CC) {
        int aux = blockIdx.x - BB * CC;
        if (aux < 384) {                         // pw weight fp32->bf16 prep
            int idx = aux * 256 + threadIdx.x;   // 6*16384 = 384*256
            int mat = idx >> 14, e = idx & 16383;
            const float* src; float s = 1.f;
            switch (mat) {                       // block-uniform
                case 0:  src = pw0; s = BN_SCALE; break;  // sc3_p1 (mid, BN folded)
                case 1:  src = pw1; s = BN_SCALE; break;  // sc5_p1
                case 2:  src = pw2; break;                // sc3_p2
                case 3:  src = pw3; break;                // sc5_p2
                case 4:  src = pw4; break;                // dc3_p
                default: src = pw5; break;                // dc5_p
            }
            Wbf[idx] = f2us(src[e] * s);
        } else if (threadIdx.x < BB) {           // gate-buffer role block
            int b = threadIdx.x;
            float g[8];
            compute_gates(wlog, topp, b, g);
            #pragma unroll
            for (int i = 0; i < 8; ++i) {
                out_w[b * 8 + i] = wlog[b * 8 + i];   // output 1: logit clone
                gates[b * 8 + i] = g[i];
            }
            int n = 0;
            #pragma unroll
            for (int i = 4; i < 8; ++i)
                if (g[i] > 0.f) { if (n < 4) cops[b * 4 + n] = i; ++n; }
            cnum[b] = (n < 4) ? n : 4;
        }
        return;
    }
    int plane = blockIdx.x;            // b*128 + c
    int b = plane >> 7, c = plane & 127;
    float g[8];
    compute_gates(wlog, topp, b, g);   // inline: no producer-kernel dependency
    float g1 = g[1] * BN_SCALE;
    float g2 = g[2] * BN_SCALE;
    float g3 = g[3];
    float g4 = g[4], g5 = g[5], g6 = g[6], g7 = g[7];
    bool haspool = (g1 != 0.f) | (g2 != 0.f) | (g3 != 0.f);
    bool hasdw   = (g4 != 0.f) | (g5 != 0.f) | (g6 != 0.f) | (g7 != 0.f);
    float* op = out + (size_t)plane * PLANE;
    if (!haspool && !hasdw) {
        ((float4*)op)[threadIdx.x] = make_float4(0.f, 0.f, 0.f, 0.f);
        return;
    }
    __shared__ float sxr[PLANE];       // raw x (pools/skip)
    __shared__ float sxf[PLANE];       // relu(x) (dw)
    {
        float4 v = ((const float4*)(x + (size_t)plane * PLANE))[threadIdx.x];
        ((float4*)sxr)[threadIdx.x] = v;
        ((float4*)sxf)[threadIdx.x] =
            make_float4(fmaxf(v.x, 0.f), fmaxf(v.y, 0.f),
                        fmaxf(v.z, 0.f), fmaxf(v.w, 0.f));
    }
    __syncthreads();

    // ---- out init: pools + skip (or zeros)
    if (haspool) {
        #pragma unroll
        for (int j = 0; j < 4; ++j) {
            int px = threadIdx.x + j * 256;
            int h = px >> 5, w = px & 31;
            float mx = -3.4e38f, sm = 0.f;
            int cnt = 0;
            #pragma unroll
            for (int dh = -1; dh <= 1; ++dh) {
                int ih = h + dh;
                if ((unsigned)ih >= HH) continue;
                #pragma unroll
                for (int dw = -1; dw <= 1; ++dw) {
                    int iw = w + dw;
                    if ((unsigned)iw >= WW) continue;
                    float v = sxr[ih * WW + iw];
                    mx = fmaxf(mx, v);
                    sm += v;
                    ++cnt;
                }
            }
            op[px] = g1 * mx + g2 * (sm / (float)cnt) + g3 * sxr[px];
        }
    } else {
        ((float4*)op)[threadIdx.x] = make_float4(0.f, 0.f, 0.f, 0.f);
    }

    // ---- first dw for gated conv ops
    size_t off = (size_t)plane * PLANE;
    if (g4 != 0.f) dw_comp<3, 1>(sxf, w4, c, A4 + off);
    if (g5 != 0.f) dw_comp<5, 1>(sxf, w5, c, A5 + off);
    if (g6 != 0.f) dw_comp<3, 2>(sxf, w6, c, P6 + off);
    if (g7 != 0.f) dw_comp<5, 2>(sxf, w7, c, P7 + off);
}

// ---------------- MFMA pw building blocks -------------------------------
// Orientation: m=hw, n=co. A = In^T tile (LDS, 64hw x 128ci, row stride 130
// ushorts = 65 dwords -> bank stride 1), B = W bf16 (direct global, L2-hot).

__device__ __forceinline__ void stage_bt(unsigned int* __restrict__ BtU,
                                         const unsigned short* __restrict__ A,
                                         int hw0, float s) {
    unsigned short* Bs = (unsigned short*)BtU;
    #pragma unroll
    for (int i = 0; i < 16; ++i) {
        int idx = threadIdx.x + i * 256;       // 4096 = 128ci x 32 hw-pairs
        int ci = idx >> 5, p = idx & 31;
        unsigned int raw = *(const unsigned int*)(A + (size_t)ci * PLANE + hw0 + 2 * p);
        Bs[(2 * p) * 130 + ci]     = f2us(us2f(raw) * s);
        Bs[(2 * p + 1) * 130 + ci] = f2us(us2f(raw >> 16) * s);
    }
}

// zero-padded variant for halo rows (hw0 may run off the plane)
__device__ __forceinline__ void stage_bt_z(unsigned int* __restrict__ BtU,
                                           const unsigned short* __restrict__ A,
                                           int hw0) {
    unsigned short* Bs = (unsigned short*)BtU;
    #pragma unroll
    for (int i = 0; i < 16; ++i) {
        int idx = threadIdx.x + i * 256;
        int ci = idx >> 5, p = idx & 31;
        int pg = hw0 + 2 * p;
        unsigned int raw = 0u;
        if ((unsigned)pg < (unsigned)PLANE)
            raw = *(const unsigned int*)(A + (size_t)ci * PLANE + pg);
        Bs[(2 * p) * 130 + ci]     = (unsigned short)(raw & 0xffffu);
        Bs[(2 * p + 1) * 130 + ci] = (unsigned short)(raw >> 16);
    }
}

__device__ __forceinline__ bf16x8 afrag(const unsigned int* __restrict__ BtU,
                                        int r, int ko2) {
    union { unsigned int u[4]; bf16x8 v; } f;
    #pragma unroll
    for (int j = 0; j < 4; ++j) f.u[j] = BtU[r * 65 + ko2 + j];
    return f.v;
}

// ---- fused sep-conv tail: mid-pw over K+1 halo rows (MFMA, B kept in LDS,
//      relu'd bf16), then depthwise KxK via chunked register sliding window
//      (8 cols/chunk keeps VGPRs in budget -- R11 spilled here), output
//      (scaled by gs) into the BtU staging buffer for the final MFMA.
template <int K>
__device__ __forceinline__ void
sep_to_bt(unsigned int* __restrict__ BtU, unsigned short* __restrict__ Braw,
          const unsigned short* __restrict__ Asrc,
          const unsigned short* __restrict__ Wmid,
          const float* __restrict__ wd, int hwt, float gs) {
    constexpr int PAD = K / 2, NR = K + 1, NSEG = NR / 2, S = 196;
    int wave = threadIdx.x >> 6, lane = threadIdx.x & 63;
    int q = lane >> 4, mm = lane & 15;
    int r = wave * 16 + mm;
    int rbase = 2 * hwt - PAD;                 // first staged image row
    for (int seg = 0; seg < NSEG; ++seg) {
        if (seg) __syncthreads();              // prev seg's afrag reads done
        stage_bt_z(BtU, Asrc, rbase * 32 + seg * 64);
        __syncthreads();
        f32x4 accB[8];
        #pragma unroll
        for (int i = 0; i < 8; ++i) accB[i] = (f32x4){0.f, 0.f, 0.f, 0.f};
        #pragma unroll
        for (int kb = 0; kb < 4; ++kb) {
            bf16x8 a = afrag(BtU, r, kb * 16 + q * 4);
            #pragma unroll
            for (int nt = 0; nt < 8; ++nt) {
                bf16x8 bv = *(const bf16x8*)(Wmid + (nt * 16 + mm) * CC + kb * 32 + q * 8);
                accB[nt] = __builtin_amdgcn_mfma_f32_16x16x32_bf16(a, bv, accB[nt], 0, 0, 0);
            }
        }
        int pxb = seg * 64 + wave * 16 + q * 4;   // local px within NR rows
        #pragma unroll
        for (int nt = 0; nt < 8; ++nt) {
            int co = nt * 16 + mm;
            ushort4 v;
            v.x = f2us(fmaxf(accB[nt][0], 0.f));   // relu folded (bit-equal to
            v.y = f2us(fmaxf(accB[nt][1], 0.f));   // round-then-relu for bf16)
            v.z = f2us(fmaxf(accB[nt][2], 0.f));
            v.w = f2us(fmaxf(accB[nt][3], 0.f));
            *(ushort4*)(Braw + (size_t)co * S + pxb) = v;
        }
    }
    __syncthreads();                           // Braw complete; BtU free

    // depthwise KxK: thread's channel fixed -> weights in VGPRs. Chunked
    // 8-col sliding window: acc[8]+win[16]+wk[K*K] stays within VGPR budget
    // (R11's acc[32]+win[40] spilled to scratch: 190MB writes). Per-output
    // FMA order (ky outer, kx inner) identical -> bit-identical results.
    int ci = threadIdx.x & 127, h = threadIdx.x >> 7;   // h: output row 2t+h
    float wk[K * K];
    #pragma unroll
    for (int i = 0; i < K * K; ++i) wk[i] = wd[ci * K * K + i];
    const unsigned short* rowp = Braw + (size_t)ci * S + h * 32;
    unsigned short* Bs = (unsigned short*)BtU;
    #pragma unroll
    for (int w0 = 0; w0 < 32; w0 += 8) {
        float acc[8];
        #pragma unroll
        for (int w = 0; w < 8; ++w) acc[w] = 0.f;
        #pragma unroll
        for (int ky = 0; ky < K; ++ky) {       // input row = h + ky
            float win[16];                     // cols w0-4 .. w0+11
            #pragma unroll
            for (int k = 0; k < 4; ++k) {
                int col = w0 - 4 + 4 * k;      // 4-col groups: all-in or all-out
                if ((unsigned)col < 32u) {
                    ushort4 v = *(const ushort4*)(rowp + ky * 32 + col);
                    win[4*k]   = us2f(v.x);
                    win[4*k+1] = us2f(v.y);
                    win[4*k+2] = us2f(v.z);
                    win[4*k+3] = us2f(v.w);
                } else {
                    win[4*k] = win[4*k+1] = win[4*k+2] = win[4*k+3] = 0.f;
                }
            }
            #pragma unroll
            for (int kx = 0; kx < K; ++kx) {
                float f = wk[ky * K + kx];
                #pragma unroll
                for (int w = 0; w < 8; ++w)
                    acc[w] = fmaf(f, win[w + kx - PAD + 4], acc[w]);
            }
        }
        #pragma unroll
        for (int w = 0; w < 8; ++w)
            Bs[(h * 32 + w0 + w) * 130 + ci] = f2us(acc[w] * gs);
    }
    __syncthreads();                           // BtU ready for final MFMA
}

// ------------- K2: fused mid-pw + dw2 + final-pw, float4 RMW into out
__global__ __launch_bounds__(256, 2) void
k_tail(const unsigned short* __restrict__ A4,
       const unsigned short* __restrict__ A5,
       const unsigned short* __restrict__ P6,
       const unsigned short* __restrict__ P7,
       const unsigned short* __restrict__ Wbf,
       const float* __restrict__ gates,
       const int* __restrict__ cnum, const int* __restrict__ cops,
       const float* __restrict__ wd3, const float* __restrict__ wd5,
       float* __restrict__ out) {
    int blk = blockIdx.x;              // b*16 + hwt
    int hwt = blk & 15;
    int b = blk >> 4;
    int n = cnum[b];
    if (n == 0) return;                // out already holds pools/skip/zeros
    int hw0 = hwt * 64;
    int wave = threadIdx.x >> 6, lane = threadIdx.x & 63;
    int q = lane >> 4, mm = lane & 15;
    int r = wave * 16 + mm;
    __shared__ unsigned int BtU[64 * 65];           // 16.6 KB
    __shared__ unsigned short Braw[128 * 196];      // 50.2 KB (stride 196us:
                                                    // dword-stride 98 -> b64
                                                    // lanes conflict-free)
    f32x4 acc[8];
    #pragma unroll
    for (int i = 0; i < 8; ++i) acc[i] = (f32x4){0.f, 0.f, 0.f, 0.f};
    for (int t = 0; t < n; ++t) {
        int op = cops[b * 4 + t];
        float gs = gates[b * 8 + op] * BN_SCALE;
        if (t) __syncthreads();        // prev op's BtU readers done
        if (op >= 6) {                 // dil convs: dw already done (P6/P7)
            stage_bt(BtU, (op == 6 ? P6 : P7) + (size_t)b * SAMP, hw0, gs);
            __syncthreads();
        } else if (op == 4) {
            sep_to_bt<3>(BtU, Braw, A4 + (size_t)b * SAMP, Wbf, wd3, hwt, gs);
        } else {
            sep_to_bt<5>(BtU, Braw, A5 + (size_t)b * SAMP, Wbf + 16384, wd5, hwt, gs);
        }
        const unsigned short* Wb = Wbf + (op - 2) * 16384;
        #pragma unroll
        for (int kb = 0; kb < 4; ++kb) {
            bf16x8 a = afrag(BtU, r, kb * 16 + q * 4);
            #pragma unroll
            for (int nt = 0; nt < 8; ++nt) {
                bf16x8 bv = *(const bf16x8*)(Wb + (nt * 16 + mm) * CC + kb * 32 + q * 8);
                acc[nt] = __builtin_amdgcn_mfma_f32_16x16x32_bf16(a, bv, acc[nt], 0, 0, 0);
            }
        }
    }
    int hwbase = hw0 + wave * 16 + q * 4;
    #pragma unroll
    for (int nt = 0; nt < 8; ++nt) {
        int co = nt * 16 + mm;
        float* p = out + (size_t)(b * CC + co) * PLANE + hwbase;
        float4 o = *(float4*)p;
        o.x += acc[nt][0]; o.y += acc[nt][1];
        o.z += acc[nt][2]; o.w += acc[nt][3];
        *(float4*)p = o;
    }
}

// ---------------------------------------------------------------- launch
extern "C" void kernel_launch(void* const* d_in, const int* in_sizes, int n_in,
                              void* d_out, int out_size, void* d_ws, size_t ws_size,
                              hipStream_t stream) {
    const float* x      = (const float*)d_in[0];
    const float* wlog   = (const float*)d_in[1];
    const float* sc3_d1 = (const float*)d_in[2];
    const float* sc3_p1 = (const float*)d_in[3];
    const float* sc3_d2 = (const float*)d_in[4];
    const float* sc3_p2 = (const float*)d_in[5];
    const float* sc5_d1 = (const float*)d_in[6];
    const float* sc5_p1 = (const float*)d_in[7];
    const float* sc5_d2 = (const float*)d_in[8];
    const float* sc5_p2 = (const float*)d_in[9];
    const float* dc3_d  = (const float*)d_in[10];
    const float* dc3_p  = (const float*)d_in[11];
    const float* dc5_d  = (const float*)d_in[12];
    const float* dc5_p  = (const float*)d_in[13];
    const void* topp    = d_in[14];

    float* out  = (float*)d_out;
    float* outw = out + NOUT0;

    float* gates = (float*)d_ws;
    int*   cnum  = (int*)((char*)d_ws + 2048);
    int*   cops  = (int*)((char*)d_ws + 2304);
    unsigned short* Wbf  = (unsigned short*)((char*)d_ws + 4096);   // 6*32KB
    unsigned short* base = (unsigned short*)((char*)d_ws + 200704);
    unsigned short* A4 = base;
    unsigned short* A5 = base + (size_t)NOUT0;
    unsigned short* P6 = base + (size_t)NOUT0 * 2;
    unsigned short* P7 = base + (size_t)NOUT0 * 3;

    k_front_all<<<BB * CC + 385, 256, 0, stream>>>(
        x, sc3_d1, sc5_d1, dc3_d, dc5_d,
        wlog, topp,
        sc3_p1, sc5_p1, sc3_p2, sc5_p2, dc3_p, dc5_p,
        gates, cnum, cops, outw, Wbf,
        out, A4, A5, P6, P7);
    k_tail<<<BB * 16, 256, 0, stream>>>(A4, A5, P6, P7, Wbf,
                                        gates, cnum, cops,
                                        sc3_d2, sc5_d2, out);
}

// Round 3
// 226.741 us; speedup vs baseline: 1.1870x; 1.1659x over previous
//
#include <hip/hip_runtime.h>
#include <hip/hip_bf16.h>

// DARTS MixedOp. B=64, C=128, H=W=32. Per-sample top-k(2) masked-softmax gate
// over 8 ops. Inputs fp32, outputs fp32.
//
// R13: same 2-dispatch structure as R11/R12; attacks k_tail's scratch spill
//  at the register BUDGET: R11/R12 showed VGPR_Count pinned at exactly 128
//  (the __launch_bounds__(256,2) cap) with ~180MB of scratch writes that
//  did NOT respond to dw-window chunking -> peak pressure is in the
//  software-pipelined stage+MFMA region, and the 128 cap is the cause.
//  (a) launch_bounds pin removed (LDS 67KB already caps at 2 blocks/CU);
//  (b) stage loops unroll-capped to 4 (4 loads in flight, not 16).
//  Math order unchanged -> bit-identical output.
//
// ws: gates @0 | cnum @2048 | cops @2304 | Wbf[6][128][128] bf16 @4096 |
// 4 bf16 bufs of 16.8MB @200704 (A4 A5 P6 P7) = ~67MB.

#define BN_SCALE 0.9999950000374997f  // 1/sqrt(1+1e-5)
#define BB 64
#define CC 128
#define HH 32
#define WW 32
#define PLANE (HH*WW)          // 1024
#define SAMP (CC*PLANE)        // 131072
#define NOUT0 (BB*SAMP)        // 8388608

typedef __attribute__((ext_vector_type(8))) short bf16x8;
typedef __attribute__((ext_vector_type(4))) float f32x4;

__device__ __forceinline__ float us2f(unsigned int u) {
    unsigned int x = (u & 0xffffu) << 16;
    float f; __builtin_memcpy(&f, &x, 4); return f;
}
__device__ __forceinline__ unsigned short f2us(float f) {
    __hip_bfloat16 h = __float2bfloat16(f);
    unsigned short u; __builtin_memcpy(&u, &h, 2); return u;
}

// ---------------------------------------------------------------- gates
// Identical math everywhere (deterministic) so inline copies agree with the
// buffer written by the role block.
__device__ __forceinline__ void compute_gates(const float* __restrict__ wlog,
                                              const void* __restrict__ topp,
                                              int b, float* g) {
    int top = -1;                           // robust `top` parse
    {
        unsigned int u0 = *(const unsigned int*)topp;
        int i32 = (int)u0;
        if (i32 >= 1 && i32 <= 8) top = i32;
        else {
            float f32v; __builtin_memcpy(&f32v, &u0, 4);
            if (f32v >= 1.f && f32v <= 8.f) top = (int)(f32v + 0.5f);
            else { float fb = us2f(u0); if (fb >= 1.f && fb <= 8.f) top = (int)(fb + 0.5f); }
        }
        if (top < 1 || top > 8) top = 2;
    }
    float lw[8];
    #pragma unroll
    for (int i = 0; i < 8; ++i) lw[i] = wlog[b * 8 + i];
    bool sel[8] = {false,false,false,false,false,false,false,false};
    for (int t = 0; t < top; ++t) {         // lax.top_k tie-break: lowest index
        int best = -1; float bv = -3.4e38f;
        #pragma unroll
        for (int i = 0; i < 8; ++i)
            if (!sel[i] && lw[i] > bv) { bv = lw[i]; best = i; }
        if (best >= 0) sel[best] = true;
    }
    float m = -3.4e38f;
    #pragma unroll
    for (int i = 0; i < 8; ++i) if (sel[i] && lw[i] > m) m = lw[i];
    float s = 0.f, e[8];
    #pragma unroll
    for (int i = 0; i < 8; ++i) { e[i] = sel[i] ? expf(lw[i] - m) : 0.f; s += e[i]; }
    float inv = (s > 0.f) ? 1.f / s : 0.f;
    #pragma unroll
    for (int i = 0; i < 8; ++i)
        g[i] = (s > 0.f) ? e[i] * inv : (sel[i] ? 1.f / (float)top : 0.f);
}

// ------------------------------------------- depthwise conv helper (K1)
template <int K, int DIL>
__device__ __forceinline__ void dw_comp(const float* __restrict__ sx,
                                        const float* __restrict__ wd, int c,
                                        unsigned short* __restrict__ opp) {
    constexpr int PAD = (K / 2) * DIL;
    float wk[K * K];
    #pragma unroll
    for (int i = 0; i < K * K; ++i) wk[i] = wd[c * K * K + i];
    #pragma unroll
    for (int j = 0; j < 4; ++j) {
        int px = threadIdx.x + j * 256;
        int h = px >> 5, w = px & 31;
        float acc = 0.f;
        #pragma unroll
        for (int ky = 0; ky < K; ++ky) {
            int ih = h + ky * DIL - PAD;
            if ((unsigned)ih >= HH) continue;
            #pragma unroll
            for (int kx = 0; kx < K; ++kx) {
                int iw = w + kx * DIL - PAD;
                if ((unsigned)iw >= WW) continue;
                acc = fmaf(wk[ky * K + kx], sx[ih * WW + iw], acc);
            }
        }
        opp[px] = f2us(acc);
    }
}

// ------- K1: pools + skip + out init + first dw of all 4 conv ops,
//             plus (aux blocks) weight prep and gate-buffer writes.
__global__ __launch_bounds__(256) void
k_front_all(const float* __restrict__ x,
            const float* __restrict__ w4, const float* __restrict__ w5,
            const float* __restrict__ w6, const float* __restrict__ w7,
            const float* __restrict__ wlog, const void* __restrict__ topp,
            const float* __restrict__ pw0, const float* __restrict__ pw1,
            const float* __restrict__ pw2, const float* __restrict__ pw3,
            const float* __restrict__ pw4, const float* __restrict__ pw5,
            float* __restrict__ gates,
            int* __restrict__ cnum, int* __restrict__ cops,
            float* __restrict__ out_w,
            unsigned short* __restrict__ Wbf,
            float* __restrict__ out,
            unsigned short* __restrict__ A4, unsigned short* __restrict__ A5,
            unsigned short* __restrict__ P6, unsigned short* __restrict__ P7) {
    if (blockIdx.x >= BB * CC) {
        int aux = blockIdx.x - BB * CC;
        if (aux < 384) {                         // pw weight fp32->bf16 prep
            int idx = aux * 256 + threadIdx.x;   // 6*16384 = 384*256
            int mat = idx >> 14, e = idx & 16383;
            const float* src; float s = 1.f;
            switch (mat) {                       // block-uniform
                case 0:  src = pw0; s = BN_SCALE; break;  // sc3_p1 (mid, BN folded)
                case 1:  src = pw1; s = BN_SCALE; break;  // sc5_p1
                case 2:  src = pw2; break;                // sc3_p2
                case 3:  src = pw3; break;                // sc5_p2
                case 4:  src = pw4; break;                // dc3_p
                default: src = pw5; break;                // dc5_p
            }
            Wbf[idx] = f2us(src[e] * s);
        } else if (threadIdx.x < BB) {           // gate-buffer role block
            int b = threadIdx.x;
            float g[8];
            compute_gates(wlog, topp, b, g);
            #pragma unroll
            for (int i = 0; i < 8; ++i) {
                out_w[b * 8 + i] = wlog[b * 8 + i];   // output 1: logit clone
                gates[b * 8 + i] = g[i];
            }
            int n = 0;
            #pragma unroll
            for (int i = 4; i < 8; ++i)
                if (g[i] > 0.f) { if (n < 4) cops[b * 4 + n] = i; ++n; }
            cnum[b] = (n < 4) ? n : 4;
        }
        return;
    }
    int plane = blockIdx.x;            // b*128 + c
    int b = plane >> 7, c = plane & 127;
    float g[8];
    compute_gates(wlog, topp, b, g);   // inline: no producer-kernel dependency
    float g1 = g[1] * BN_SCALE;
    float g2 = g[2] * BN_SCALE;
    float g3 = g[3];
    float g4 = g[4], g5 = g[5], g6 = g[6], g7 = g[7];
    bool haspool = (g1 != 0.f) | (g2 != 0.f) | (g3 != 0.f);
    bool hasdw   = (g4 != 0.f) | (g5 != 0.f) | (g6 != 0.f) | (g7 != 0.f);
    float* op = out + (size_t)plane * PLANE;
    if (!haspool && !hasdw) {
        ((float4*)op)[threadIdx.x] = make_float4(0.f, 0.f, 0.f, 0.f);
        return;
    }
    __shared__ float sxr[PLANE];       // raw x (pools/skip)
    __shared__ float sxf[PLANE];       // relu(x) (dw)
    {
        float4 v = ((const float4*)(x + (size_t)plane * PLANE))[threadIdx.x];
        ((float4*)sxr)[threadIdx.x] = v;
        ((float4*)sxf)[threadIdx.x] =
            make_float4(fmaxf(v.x, 0.f), fmaxf(v.y, 0.f),
                        fmaxf(v.z, 0.f), fmaxf(v.w, 0.f));
    }
    __syncthreads();

    // ---- out init: pools + skip (or zeros)
    if (haspool) {
        #pragma unroll
        for (int j = 0; j < 4; ++j) {
            int px = threadIdx.x + j * 256;
            int h = px >> 5, w = px & 31;
            float mx = -3.4e38f, sm = 0.f;
            int cnt = 0;
            #pragma unroll
            for (int dh = -1; dh <= 1; ++dh) {
                int ih = h + dh;
                if ((unsigned)ih >= HH) continue;
                #pragma unroll
                for (int dw = -1; dw <= 1; ++dw) {
                    int iw = w + dw;
                    if ((unsigned)iw >= WW) continue;
                    float v = sxr[ih * WW + iw];
                    mx = fmaxf(mx, v);
                    sm += v;
                    ++cnt;
                }
            }
            op[px] = g1 * mx + g2 * (sm / (float)cnt) + g3 * sxr[px];
        }
    } else {
        ((float4*)op)[threadIdx.x] = make_float4(0.f, 0.f, 0.f, 0.f);
    }

    // ---- first dw for gated conv ops
    size_t off = (size_t)plane * PLANE;
    if (g4 != 0.f) dw_comp<3, 1>(sxf, w4, c, A4 + off);
    if (g5 != 0.f) dw_comp<5, 1>(sxf, w5, c, A5 + off);
    if (g6 != 0.f) dw_comp<3, 2>(sxf, w6, c, P6 + off);
    if (g7 != 0.f) dw_comp<5, 2>(sxf, w7, c, P7 + off);
}

// ---------------- MFMA pw building blocks -------------------------------
// Orientation: m=hw, n=co. A = In^T tile (LDS, 64hw x 128ci, row stride 130
// ushorts = 65 dwords -> bank stride 1), B = W bf16 (direct global, L2-hot).
// Stage loops unroll-capped at 4: 16-deep unroll kept 16 loads + 16 addrs
// live -> peak-VGPR spill under the (removed) 128 cap; 4-deep is plenty
// with 8 resident waves.

__device__ __forceinline__ void stage_bt(unsigned int* __restrict__ BtU,
                                         const unsigned short* __restrict__ A,
                                         int hw0, float s) {
    unsigned short* Bs = (unsigned short*)BtU;
    #pragma unroll 4
    for (int i = 0; i < 16; ++i) {
        int idx = threadIdx.x + i * 256;       // 4096 = 128ci x 32 hw-pairs
        int ci = idx >> 5, p = idx & 31;
        unsigned int raw = *(const unsigned int*)(A + (size_t)ci * PLANE + hw0 + 2 * p);
        Bs[(2 * p) * 130 + ci]     = f2us(us2f(raw) * s);
        Bs[(2 * p + 1) * 130 + ci] = f2us(us2f(raw >> 16) * s);
    }
}

// zero-padded variant for halo rows (hw0 may run off the plane)
__device__ __forceinline__ void stage_bt_z(unsigned int* __restrict__ BtU,
                                           const unsigned short* __restrict__ A,
                                           int hw0) {
    unsigned short* Bs = (unsigned short*)BtU;
    #pragma unroll 4
    for (int i = 0; i < 16; ++i) {
        int idx = threadIdx.x + i * 256;
        int ci = idx >> 5, p = idx & 31;
        int pg = hw0 + 2 * p;
        unsigned int raw = 0u;
        if ((unsigned)pg < (unsigned)PLANE)
            raw = *(const unsigned int*)(A + (size_t)ci * PLANE + pg);
        Bs[(2 * p) * 130 + ci]     = (unsigned short)(raw & 0xffffu);
        Bs[(2 * p + 1) * 130 + ci] = (unsigned short)(raw >> 16);
    }
}

__device__ __forceinline__ bf16x8 afrag(const unsigned int* __restrict__ BtU,
                                        int r, int ko2) {
    union { unsigned int u[4]; bf16x8 v; } f;
    #pragma unroll
    for (int j = 0; j < 4; ++j) f.u[j] = BtU[r * 65 + ko2 + j];
    return f.v;
}

// ---- fused sep-conv tail: mid-pw over K+1 halo rows (MFMA, B kept in LDS,
//      relu'd bf16), then depthwise KxK via chunked register sliding window
//      (8 cols/chunk), output (scaled by gs) into BtU for the final MFMA.
template <int K>
__device__ __forceinline__ void
sep_to_bt(unsigned int* __restrict__ BtU, unsigned short* __restrict__ Braw,
          const unsigned short* __restrict__ Asrc,
          const unsigned short* __restrict__ Wmid,
          const float* __restrict__ wd, int hwt, float gs) {
    constexpr int PAD = K / 2, NR = K + 1, NSEG = NR / 2, S = 196;
    int wave = threadIdx.x >> 6, lane = threadIdx.x & 63;
    int q = lane >> 4, mm = lane & 15;
    int r = wave * 16 + mm;
    int rbase = 2 * hwt - PAD;                 // first staged image row
    for (int seg = 0; seg < NSEG; ++seg) {
        if (seg) __syncthreads();              // prev seg's afrag reads done
        stage_bt_z(BtU, Asrc, rbase * 32 + seg * 64);
        __syncthreads();
        f32x4 accB[8];
        #pragma unroll
        for (int i = 0; i < 8; ++i) accB[i] = (f32x4){0.f, 0.f, 0.f, 0.f};
        #pragma unroll
        for (int kb = 0; kb < 4; ++kb) {
            bf16x8 a = afrag(BtU, r, kb * 16 + q * 4);
            #pragma unroll
            for (int nt = 0; nt < 8; ++nt) {
                bf16x8 bv = *(const bf16x8*)(Wmid + (nt * 16 + mm) * CC + kb * 32 + q * 8);
                accB[nt] = __builtin_amdgcn_mfma_f32_16x16x32_bf16(a, bv, accB[nt], 0, 0, 0);
            }
        }
        int pxb = seg * 64 + wave * 16 + q * 4;   // local px within NR rows
        #pragma unroll
        for (int nt = 0; nt < 8; ++nt) {
            int co = nt * 16 + mm;
            ushort4 v;
            v.x = f2us(fmaxf(accB[nt][0], 0.f));   // relu folded (bit-equal to
            v.y = f2us(fmaxf(accB[nt][1], 0.f));   // round-then-relu for bf16)
            v.z = f2us(fmaxf(accB[nt][2], 0.f));
            v.w = f2us(fmaxf(accB[nt][3], 0.f));
            *(ushort4*)(Braw + (size_t)co * S + pxb) = v;
        }
    }
    __syncthreads();                           // Braw complete; BtU free

    // depthwise KxK: thread's channel fixed -> weights in VGPRs. Chunked
    // 8-col sliding window (acc[8]+win[16]+wk[K*K]). Per-output FMA order
    // (ky outer, kx inner) identical -> bit-identical results.
    int ci = threadIdx.x & 127, h = threadIdx.x >> 7;   // h: output row 2t+h
    float wk[K * K];
    #pragma unroll
    for (int i = 0; i < K * K; ++i) wk[i] = wd[ci * K * K + i];
    const unsigned short* rowp = Braw + (size_t)ci * S + h * 32;
    unsigned short* Bs = (unsigned short*)BtU;
    #pragma unroll
    for (int w0 = 0; w0 < 32; w0 += 8) {
        float acc[8];
        #pragma unroll
        for (int w = 0; w < 8; ++w) acc[w] = 0.f;
        #pragma unroll
        for (int ky = 0; ky < K; ++ky) {       // input row = h + ky
            float win[16];                     // cols w0-4 .. w0+11
            #pragma unroll
            for (int k = 0; k < 4; ++k) {
                int col = w0 - 4 + 4 * k;      // 4-col groups: all-in or all-out
                if ((unsigned)col < 32u) {
                    ushort4 v = *(const ushort4*)(rowp + ky * 32 + col);
                    win[4*k]   = us2f(v.x);
                    win[4*k+1] = us2f(v.y);
                    win[4*k+2] = us2f(v.z);
                    win[4*k+3] = us2f(v.w);
                } else {
                    win[4*k] = win[4*k+1] = win[4*k+2] = win[4*k+3] = 0.f;
                }
            }
            #pragma unroll
            for (int kx = 0; kx < K; ++kx) {
                float f = wk[ky * K + kx];
                #pragma unroll
                for (int w = 0; w < 8; ++w)
                    acc[w] = fmaf(f, win[w + kx - PAD + 4], acc[w]);
            }
        }
        #pragma unroll
        for (int w = 0; w < 8; ++w)
            Bs[(h * 32 + w0 + w) * 130 + ci] = f2us(acc[w] * gs);
    }
    __syncthreads();                           // BtU ready for final MFMA
}

// ------------- K2: fused mid-pw + dw2 + final-pw, float4 RMW into out
// No min-occupancy pin: LDS (67KB) already caps residency at 2 blocks/CU;
// the old (256,2) pin capped VGPRs at 128 and caused the spill loop.
__global__ __launch_bounds__(256) void
k_tail(const unsigned short* __restrict__ A4,
       const unsigned short* __restrict__ A5,
       const unsigned short* __restrict__ P6,
       const unsigned short* __restrict__ P7,
       const unsigned short* __restrict__ Wbf,
       const float* __restrict__ gates,
       const int* __restrict__ cnum, const int* __restrict__ cops,
       const float* __restrict__ wd3, const float* __restrict__ wd5,
       float* __restrict__ out) {
    int blk = blockIdx.x;              // b*16 + hwt
    int hwt = blk & 15;
    int b = blk >> 4;
    int n = cnum[b];
    if (n == 0) return;                // out already holds pools/skip/zeros
    int hw0 = hwt * 64;
    int wave = threadIdx.x >> 6, lane = threadIdx.x & 63;
    int q = lane >> 4, mm = lane & 15;
    int r = wave * 16 + mm;
    __shared__ unsigned int BtU[64 * 65];           // 16.6 KB
    __shared__ unsigned short Braw[128 * 196];      // 50.2 KB (stride 196us:
                                                    // dword-stride 98 -> b64
                                                    // lanes conflict-free)
    f32x4 acc[8];
    #pragma unroll
    for (int i = 0; i < 8; ++i) acc[i] = (f32x4){0.f, 0.f, 0.f, 0.f};
    for (int t = 0; t < n; ++t) {
        int op = cops[b * 4 + t];
        float gs = gates[b * 8 + op] * BN_SCALE;
        if (t) __syncthreads();        // prev op's BtU readers done
        if (op >= 6) {                 // dil convs: dw already done (P6/P7)
            stage_bt(BtU, (op == 6 ? P6 : P7) + (size_t)b * SAMP, hw0, gs);
            __syncthreads();
        } else if (op == 4) {
            sep_to_bt<3>(BtU, Braw, A4 + (size_t)b * SAMP, Wbf, wd3, hwt, gs);
        } else {
            sep_to_bt<5>(BtU, Braw, A5 + (size_t)b * SAMP, Wbf + 16384, wd5, hwt, gs);
        }
        const unsigned short* Wb = Wbf + (op - 2) * 16384;
        #pragma unroll
        for (int kb = 0; kb < 4; ++kb) {
            bf16x8 a = afrag(BtU, r, kb * 16 + q * 4);
            #pragma unroll
            for (int nt = 0; nt < 8; ++nt) {
                bf16x8 bv = *(const bf16x8*)(Wb + (nt * 16 + mm) * CC + kb * 32 + q * 8);
                acc[nt] = __builtin_amdgcn_mfma_f32_16x16x32_bf16(a, bv, acc[nt], 0, 0, 0);
            }
        }
    }
    int hwbase = hw0 + wave * 16 + q * 4;
    #pragma unroll
    for (int nt = 0; nt < 8; ++nt) {
        int co = nt * 16 + mm;
        float* p = out + (size_t)(b * CC + co) * PLANE + hwbase;
        float4 o = *(float4*)p;
        o.x += acc[nt][0]; o.y += acc[nt][1];
        o.z += acc[nt][2]; o.w += acc[nt][3];
        *(float4*)p = o;
    }
}

// ---------------------------------------------------------------- launch
extern "C" void kernel_launch(void* const* d_in, const int* in_sizes, int n_in,
                              void* d_out, int out_size, void* d_ws, size_t ws_size,
                              hipStream_t stream) {
    const float* x      = (const float*)d_in[0];
    const float* wlog   = (const float*)d_in[1];
    const float* sc3_d1 = (const float*)d_in[2];
    const float* sc3_p1 = (const float*)d_in[3];
    const float* sc3_d2 = (const float*)d_in[4];
    const float* sc3_p2 = (const float*)d_in[5];
    const float* sc5_d1 = (const float*)d_in[6];
    const float* sc5_p1 = (const float*)d_in[7];
    const float* sc5_d2 = (const float*)d_in[8];
    const float* sc5_p2 = (const float*)d_in[9];
    const float* dc3_d  = (const float*)d_in[10];
    const float* dc3_p  = (const float*)d_in[11];
    const float* dc5_d  = (const float*)d_in[12];
    const float* dc5_p  = (const float*)d_in[13];
    const void* topp    = d_in[14];

    float* out  = (float*)d_out;
    float* outw = out + NOUT0;

    float* gates = (float*)d_ws;
    int*   cnum  = (int*)((char*)d_ws + 2048);
    int*   cops  = (int*)((char*)d_ws + 2304);
    unsigned short* Wbf  = (unsigned short*)((char*)d_ws + 4096);   // 6*32KB
    unsigned short* base = (unsigned short*)((char*)d_ws + 200704);
    unsigned short* A4 = base;
    unsigned short* A5 = base + (size_t)NOUT0;
    unsigned short* P6 = base + (size_t)NOUT0 * 2;
    unsigned short* P7 = base + (size_t)NOUT0 * 3;

    k_front_all<<<BB * CC + 385, 256, 0, stream>>>(
        x, sc3_d1, sc5_d1, dc3_d, dc5_d,
        wlog, topp,
        sc3_p1, sc5_p1, sc3_p2, sc5_p2, dc3_p, dc5_p,
        gates, cnum, cops, outw, Wbf,
        out, A4, A5, P6, P7);
    k_tail<<<BB * 16, 256, 0, stream>>>(A4, A5, P6, P7, Wbf,
                                        gates, cnum, cops,
                                        sc3_d2, sc5_d2, out);
}